// Round 1
// baseline (630.377 us; speedup 1.0000x reference)
//
#include <hip/hip_runtime.h>

// ViewControlPreprocessor: out[r, 0:3072] = hidden[r, :]
//                          out[r, 3072 + j*16 + c] = vcc[max(4*(r%21)+j-8, 0), c]
// Fixed shapes from setup_inputs: B=1, S=1536, T_q=21, C_hidden=3072,
// N_frames=81, C_view=16, PAD_T=8, is_causal=False.

#define T_Q     21
#define C_HID   3072
#define C_VIEW  16
#define PAD_TT  8
#define ROW_F4  800   // 3200 floats / 4
#define HID_F4  768   // 3072 floats / 4

__global__ __launch_bounds__(256) void ViewControlPreprocessor_39247411151101_kernel(
    const float4* __restrict__ hid,   // (R, HID_F4)
    const float4* __restrict__ vcc,   // (N_frames, C_VIEW/4)
    float4* __restrict__ out,         // (R, ROW_F4)
    int total)
{
    int i = blockIdx.x * blockDim.x + threadIdx.x;
    if (i >= total) return;
    int r  = i / ROW_F4;             // row index (compiler: magic-mul)
    int c4 = i - r * ROW_F4;         // float4 column within row
    float4 v;
    if (c4 < HID_F4) {
        v = hid[r * HID_F4 + c4];
    } else {
        int cq = c4 - HID_F4;        // 0..31
        int j  = cq >> 2;            // window index 0..7
        int q  = cq & 3;             // float4 within the 16-float view vector
        int t  = r % T_Q;            // query-time index
        int m  = 4 * t + j;          // index into padded (len 89)
        int f  = (m < PAD_TT) ? 0 : (m - PAD_TT);  // padded[m] = vcc[max(m-8,0)]
        v = vcc[f * (C_VIEW / 4) + q];
    }
    out[i] = v;
}

extern "C" void kernel_launch(void* const* d_in, const int* in_sizes, int n_in,
                              void* d_out, int out_size, void* d_ws, size_t ws_size,
                              hipStream_t stream) {
    const float4* hid = (const float4*)d_in[0];  // hidden_states, f32
    const float4* vcc = (const float4*)d_in[1];  // view_control_condition, f32
    float4* out = (float4*)d_out;

    int rows  = in_sizes[0] / C_HID;   // 1536*21 = 32256
    int total = rows * ROW_F4;         // 25,804,800 float4s

    int block = 256;
    int grid  = (total + block - 1) / block;
    ViewControlPreprocessor_39247411151101_kernel<<<grid, block, 0, stream>>>(
        hid, vcc, out, total);
}